// Round 1
// baseline (510.794 us; speedup 1.0000x reference)
//
#include <hip/hip_runtime.h>

#define NNODES 50000
#define HID 128
#define NREL 9
#define NLAYERS 3
#define NEDGES 600000

#define NBINS (NREL * NNODES)          // 450000, bin = r*NNODES + d  (r-major!)
#define SCAN_CHUNK 1024
#define NBLK ((NBINS + SCAN_CHUNK - 1) / SCAN_CHUNK)   // 440

#define KTOT (NREL * HID)               // 1152
#define GM2 64                          // fused M-tile (rows per block)
#define FPITCH 136                      // A-tile LDS pitch in shorts (272 B rows)

typedef __attribute__((ext_vector_type(8))) short short8;
typedef __attribute__((ext_vector_type(4))) float f32x4;

__device__ __forceinline__ short f2bf(float f) {
    union { float f; unsigned u; } c; c.f = f;
    unsigned r = c.u + 0x7fff + ((c.u >> 16) & 1);   // RNE
    return (short)(r >> 16);
}
__device__ __forceinline__ float bf2f(short v) {
    return __uint_as_float(((unsigned)(unsigned short)v) << 16);
}

// ---------------- CSR build: counting sort by (rel, dest) ----------------

__global__ void hist2_kernel(const int* __restrict__ dst, const int* __restrict__ etype,
                             int* __restrict__ bins) {
    int e = blockIdx.x * blockDim.x + threadIdx.x;
    if (e < NEDGES) {
        int bin = etype[e] * NNODES + dst[e];
        atomicAdd(&bins[bin], 1);
    }
}

__global__ __launch_bounds__(256) void scan_pass1(const int* __restrict__ bins,
                                                  int* __restrict__ blocksum) {
    __shared__ int red[256];
    int b = blockIdx.x, t = threadIdx.x;
    int i0 = b * SCAN_CHUNK + t * 4;
    int s = 0;
#pragma unroll
    for (int k = 0; k < 4; k++)
        if (i0 + k < NBINS) s += bins[i0 + k];
    red[t] = s;
    __syncthreads();
    for (int off = 128; off > 0; off >>= 1) {
        if (t < off) red[t] += red[t + off];
        __syncthreads();
    }
    if (t == 0) blocksum[b] = red[0];
}

__global__ __launch_bounds__(512) void scan_pass2(const int* __restrict__ blocksum,
                                                  int* __restrict__ blockoff,
                                                  int* __restrict__ rowptr) {
    __shared__ int s[512];
    int t = threadIdx.x;
    int v = (t < NBLK) ? blocksum[t] : 0;
    s[t] = v;
    __syncthreads();
    for (int off = 1; off < 512; off <<= 1) {
        int x = (t >= off) ? s[t - off] : 0;
        __syncthreads();
        s[t] += x;
        __syncthreads();
    }
    if (t < NBLK) blockoff[t] = s[t] - v;
    if (t == 0) rowptr[NBINS] = NEDGES;
}

__global__ __launch_bounds__(256) void scan_pass3(const int* __restrict__ bins,
                                                  const int* __restrict__ blockoff,
                                                  int* __restrict__ rowptr,
                                                  int* __restrict__ cursor) {
    __shared__ int sc[256];
    int b = blockIdx.x, t = threadIdx.x;
    int i0 = b * SCAN_CHUNK + t * 4;
    int v[4], p[4];
    int s = 0;
#pragma unroll
    for (int k = 0; k < 4; k++) {
        v[k] = (i0 + k < NBINS) ? bins[i0 + k] : 0;
        p[k] = s;
        s += v[k];
    }
    sc[t] = s;
    __syncthreads();
    for (int off = 1; off < 256; off <<= 1) {
        int x = (t >= off) ? sc[t - off] : 0;
        __syncthreads();
        sc[t] += x;
        __syncthreads();
    }
    int base = blockoff[b] + (sc[t] - s);
#pragma unroll
    for (int k = 0; k < 4; k++) {
        if (i0 + k < NBINS) {
            rowptr[i0 + k] = base + p[k];
            cursor[i0 + k] = base + p[k];
        }
    }
}

__global__ void place_kernel(const int* __restrict__ dst, const int* __restrict__ src,
                             const int* __restrict__ etype,
                             int* __restrict__ cursor, int* __restrict__ bsrc) {
    int e = blockIdx.x * blockDim.x + threadIdx.x;
    if (e < NEDGES) {
        int bin = etype[e] * NNODES + dst[e];
        int pos = atomicAdd(&cursor[bin], 1);
        bsrc[pos] = src[e];
    }
}

// ---------------- converts ----------------
// Wt2[l][n][r*128+kk] = bf16(W[l][r][kk][n])   (unchanged layout; r-major K)

__global__ __launch_bounds__(256) void convert_w(const float* __restrict__ W,
                                                 short* __restrict__ Wt2) {
    int lr = blockIdx.x;
    int l = lr / NREL, r = lr - l * NREL;
    const float* w = W + (size_t)lr * HID * HID;
    short* o = Wt2 + (size_t)l * HID * KTOT;
    int tid = threadIdx.x;
#pragma unroll 4
    for (int i = 0; i < 64; i++) {
        int elem = i * 256 + tid;
        int kk = elem >> 7, n = elem & 127;
        o[(size_t)n * KTOT + r * HID + kk] = f2bf(w[elem]);
    }
}

__global__ __launch_bounds__(256) void convert_emb(const float* __restrict__ E,
                                                   short* __restrict__ Ebf) {
    int gid = blockIdx.x * blockDim.x + threadIdx.x;
    const float* p = E + (size_t)gid * 8;
    float4 v0 = *(const float4*)p;
    float4 v1 = *(const float4*)(p + 4);
    short8 o = {f2bf(v0.x), f2bf(v0.y), f2bf(v0.z), f2bf(v0.w),
                f2bf(v1.x), f2bf(v1.y), f2bf(v1.z), f2bf(v1.w)};
    *(short8*)(Ebf + (size_t)gid * 8) = o;
}

// ---------------- fused layer: gather(bin sums) + GEMM + bias + act ----------------
// Per block: 64 dest rows. Loop r=0..8: sum H[src] per (d,r) bin into regs ->
// bf16 A-tile [64][128] in LDS -> MFMA against W[r] fragments read straight
// from global (L2-resident). acc accumulates over r with identical summation
// order to the old K=1152 GEMM (r outer, k inner).
// Wave shape: 64M x 32N (wave = N-slice). C mapping (verified kernel, generalized):
//   row = mt*16 + lq*4 + reg, col = n0 + nt*16 + lm.

__global__ __launch_bounds__(256) void fused_kernel(const short* __restrict__ Hin,
                                                    const short* __restrict__ Wt2l,
                                                    const float* __restrict__ Bias, // [9][128]
                                                    const int* __restrict__ rowptr,
                                                    const int* __restrict__ bsrc,
                                                    short* __restrict__ HoutBf,     // !last
                                                    float* __restrict__ HoutF,      // last
                                                    int last) {
    __shared__ short As[GM2 * FPITCH];            // 17408 B, reused as Et
    __shared__ int   rp_s[NREL * (GM2 + 1)];      // 585 ints
    __shared__ float bias_s[NREL * HID];          // 4608 B

    int tid  = threadIdx.x;
    int wave = tid >> 6, lane = tid & 63;
    int lm = lane & 15, lq = lane >> 4;
    int row0 = blockIdx.x * GM2;
    int n0   = wave * 32;                 // wave's N base

    // stage rowptr spans (9 relations x 65 entries) and bias
    for (int i = tid; i < NREL * (GM2 + 1); i += 256) {
        int r = i / (GM2 + 1), o = i - r * (GM2 + 1);
        int d = row0 + o; if (d > NNODES) d = NNODES;   // clamp -> cnt 0 for pad rows
        rp_s[i] = rowptr[r * NNODES + d];
    }
    for (int i = tid; i < NREL * HID; i += 256) bias_s[i] = Bias[i];

    // gather mapping: 4 threads per dest row, 32 cols each
    int grow = tid >> 2;
    int gcc  = tid & 3;

    f32x4 acc[4][2];
#pragma unroll
    for (int a = 0; a < 4; a++)
#pragma unroll
        for (int b = 0; b < 2; b++) acc[a][b] = (f32x4){0.f, 0.f, 0.f, 0.f};

    __syncthreads();

    const short* wb = Wt2l + (size_t)(n0 + lm) * KTOT + lq * 8;

    for (int r = 0; r < NREL; r++) {
        // ---- gather phase (registers only; 2-edge unrolled for MLP) ----
        int rs = rp_s[r * (GM2 + 1) + grow];
        int re = rp_s[r * (GM2 + 1) + grow + 1];
        float ga[32];
#pragma unroll
        for (int i = 0; i < 32; i++) ga[i] = 0.f;
        int j = rs;
        while (j + 1 < re) {
            int s0 = bsrc[j];
            int s1 = bsrc[j + 1];
            const short8* h0 = (const short8*)(Hin + (size_t)s0 * HID + gcc * 32);
            const short8* h1 = (const short8*)(Hin + (size_t)s1 * HID + gcc * 32);
            short8 a0 = h0[0], a1 = h0[1], a2 = h0[2], a3 = h0[3];
            short8 b0 = h1[0], b1 = h1[1], b2 = h1[2], b3 = h1[3];
#pragma unroll
            for (int i = 0; i < 8; i++) {
                ga[i]      += bf2f(a0[i]) + bf2f(b0[i]);
                ga[i + 8]  += bf2f(a1[i]) + bf2f(b1[i]);
                ga[i + 16] += bf2f(a2[i]) + bf2f(b2[i]);
                ga[i + 24] += bf2f(a3[i]) + bf2f(b3[i]);
            }
            j += 2;
        }
        if (j < re) {
            int s0 = bsrc[j];
            const short8* h0 = (const short8*)(Hin + (size_t)s0 * HID + gcc * 32);
            short8 a0 = h0[0], a1 = h0[1], a2 = h0[2], a3 = h0[3];
#pragma unroll
            for (int i = 0; i < 8; i++) {
                ga[i]      += bf2f(a0[i]);
                ga[i + 8]  += bf2f(a1[i]);
                ga[i + 16] += bf2f(a2[i]);
                ga[i + 24] += bf2f(a3[i]);
            }
        }

        __syncthreads();            // prev relation's MFMA reads of As are done
        {
            short8 o0, o1, o2, o3;
#pragma unroll
            for (int i = 0; i < 8; i++) {
                o0[i] = f2bf(ga[i]);
                o1[i] = f2bf(ga[i + 8]);
                o2[i] = f2bf(ga[i + 16]);
                o3[i] = f2bf(ga[i + 24]);
            }
            short8* ap = (short8*)&As[grow * FPITCH + gcc * 32];
            ap[0] = o0; ap[1] = o1; ap[2] = o2; ap[3] = o3;
        }
        __syncthreads();

        // ---- MFMA phase: A from LDS, B fragments straight from global (L2-hot) ----
#pragma unroll
        for (int ks = 0; ks < 4; ks++) {
            short8 af[4];
#pragma unroll
            for (int mt = 0; mt < 4; mt++)
                af[mt] = *(const short8*)&As[(mt * 16 + lm) * FPITCH + ks * 32 + lq * 8];
#pragma unroll
            for (int nt = 0; nt < 2; nt++) {
                short8 bf = *(const short8*)(wb + (size_t)nt * 16 * KTOT + r * HID + ks * 32);
                __builtin_amdgcn_s_setprio(1);
#pragma unroll
                for (int mt = 0; mt < 4; mt++)
                    acc[mt][nt] = __builtin_amdgcn_mfma_f32_16x16x32_bf16(af[mt], bf, acc[mt][nt], 0, 0, 0);
                __builtin_amdgcn_s_setprio(0);
            }
        }
    }

    __syncthreads();   // final MFMA reads of As done; safe to reuse as Et

    // ---- epilogue: counts-weighted bias, activation, store ----
    if (!last) {
        short (*Et)[FPITCH] = (short(*)[FPITCH])As;
#pragma unroll
        for (int mt = 0; mt < 4; mt++) {
#pragma unroll
            for (int reg = 0; reg < 4; reg++) {
                int rl = mt * 16 + lq * 4 + reg;
                float cr[NREL];
#pragma unroll
                for (int rr = 0; rr < NREL; rr++)
                    cr[rr] = (float)(rp_s[rr * (GM2 + 1) + rl + 1] - rp_s[rr * (GM2 + 1) + rl]);
#pragma unroll
                for (int nt = 0; nt < 2; nt++) {
                    int n = n0 + nt * 16 + lm;
                    float b = 0.f;
#pragma unroll
                    for (int rr = 0; rr < NREL; rr++) b += cr[rr] * bias_s[rr * HID + n];
                    float o = fmaxf(acc[mt][nt][reg] + b, 0.f);
                    Et[rl][n] = f2bf(o);
                }
            }
        }
        __syncthreads();
#pragma unroll
        for (int i = 0; i < 4; i++) {
            int p = i * 256 + tid;
            int row = p >> 4, cc = p & 15;
            int d = row0 + row;
            if (d < NNODES)
                *(short8*)(HoutBf + (size_t)d * HID + cc * 8) = *(const short8*)&Et[row][cc * 8];
        }
    } else {
#pragma unroll
        for (int mt = 0; mt < 4; mt++) {
#pragma unroll
            for (int reg = 0; reg < 4; reg++) {
                int rl = mt * 16 + lq * 4 + reg;
                int d  = row0 + rl;
                if (d >= NNODES) continue;
                float cr[NREL];
#pragma unroll
                for (int rr = 0; rr < NREL; rr++)
                    cr[rr] = (float)(rp_s[rr * (GM2 + 1) + rl + 1] - rp_s[rr * (GM2 + 1) + rl]);
#pragma unroll
                for (int nt = 0; nt < 2; nt++) {
                    int n = n0 + nt * 16 + lm;
                    float b = 0.f;
#pragma unroll
                    for (int rr = 0; rr < NREL; rr++) b += cr[rr] * bias_s[rr * HID + n];
                    HoutF[(size_t)d * HID + n] = acc[mt][nt][reg] + b;
                }
            }
        }
    }
}

// ---------------- driver ----------------

extern "C" void kernel_launch(void* const* d_in, const int* in_sizes, int n_in,
                              void* d_out, int out_size, void* d_ws, size_t ws_size,
                              hipStream_t stream) {
    const int*   edge_index = (const int*)d_in[0];   // [2, NEDGES]: row0=dest, row1=src
    const int*   etype      = (const int*)d_in[1];
    const float* emb        = (const float*)d_in[2];
    const float* W          = (const float*)d_in[3]; // [3,9,128,128]
    const float* Bias       = (const float*)d_in[4]; // [3,9,128]
    float*       out        = (float*)d_out;

    const int* dst  = edge_index;
    const int* srcA = edge_index + NEDGES;

    // ws layout (S intermediate eliminated; H double-buffered across layers)
    short* Ebf  = (short*)d_ws;                             // 50000*128 bf16
    short* HbfA = Ebf  + (size_t)NNODES * HID;              // 50000*128 bf16
    short* HbfB = HbfA + (size_t)NNODES * HID;              // 50000*128 bf16
    short* Wt2  = HbfB + (size_t)NNODES * HID;              // 3*128*1152 bf16
    int*   bsrc     = (int*)(Wt2 + (size_t)NLAYERS * HID * KTOT);
    int*   bins     = bsrc + NEDGES;
    int*   cursor   = bins + NBINS;
    int*   rowptr   = cursor + NBINS;                       // NBINS+1
    int*   blocksum = rowptr + NBINS + 1;
    int*   blockoff = blocksum + NBLK;

    hipMemsetAsync(bins, 0, NBINS * sizeof(int), stream);
    hist2_kernel<<<(NEDGES + 255) / 256, 256, 0, stream>>>(dst, etype, bins);
    scan_pass1<<<NBLK, 256, 0, stream>>>(bins, blocksum);
    scan_pass2<<<1, 512, 0, stream>>>(blocksum, blockoff, rowptr);
    scan_pass3<<<NBLK, 256, 0, stream>>>(bins, blockoff, rowptr, cursor);
    place_kernel<<<(NEDGES + 255) / 256, 256, 0, stream>>>(dst, srcA, etype, cursor, bsrc);
    convert_w<<<NLAYERS * NREL, 256, 0, stream>>>(W, Wt2);
    convert_emb<<<(NNODES * HID / 8) / 256, 256, 0, stream>>>(emb, Ebf);

    const int nblocks = (NNODES + GM2 - 1) / GM2;   // 782
    const short* Hin = Ebf;
    for (int l = 0; l < NLAYERS; l++) {
        int last = (l + 1 == NLAYERS);
        short* Hout = (l == 0) ? HbfA : HbfB;       // alternate; never in-place
        if (l == 2) Hout = HbfA;                    // unused on last layer
        const short* Wtl = Wt2 + (size_t)l * HID * KTOT;
        const float* Bl  = Bias + (size_t)l * NREL * HID;
        fused_kernel<<<nblocks, 256, 0, stream>>>(
            Hin, Wtl, Bl, rowptr, bsrc, Hout, out, last);
        Hin = Hout;
    }
}

// Round 2
// 471.178 us; speedup vs baseline: 1.0841x; 1.0841x over previous
//
#include <hip/hip_runtime.h>

#define NNODES 50000
#define HID 128
#define NREL 9
#define NLAYERS 3
#define NEDGES 600000

#define NBINS (NREL * NNODES)          // 450000, bin = r*NNODES + d  (r-major)
#define SCAN_CHUNK 1024
#define NBLK ((NBINS + SCAN_CHUNK - 1) / SCAN_CHUNK)   // 440

#define KTOT (NREL * HID)               // 1152
#define GM2 32                          // fused M-tile (rows per block) -> 1563 blocks
#define FPITCH 136                      // A-tile LDS pitch in shorts (272 B rows, 2-way banks = free)

typedef __attribute__((ext_vector_type(8))) short short8;
typedef __attribute__((ext_vector_type(4))) float f32x4;

__device__ __forceinline__ short f2bf(float f) {
    union { float f; unsigned u; } c; c.f = f;
    unsigned r = c.u + 0x7fff + ((c.u >> 16) & 1);   // RNE
    return (short)(r >> 16);
}
__device__ __forceinline__ float bf2f(short v) {
    return __uint_as_float(((unsigned)(unsigned short)v) << 16);
}

// ---------------- CSR build: counting sort by (rel, dest) ----------------

__global__ void hist2_kernel(const int* __restrict__ dst, const int* __restrict__ etype,
                             int* __restrict__ bins) {
    int e = blockIdx.x * blockDim.x + threadIdx.x;
    if (e < NEDGES) {
        int bin = etype[e] * NNODES + dst[e];
        atomicAdd(&bins[bin], 1);
    }
}

__global__ __launch_bounds__(256) void scan_pass1(const int* __restrict__ bins,
                                                  int* __restrict__ blocksum) {
    __shared__ int red[256];
    int b = blockIdx.x, t = threadIdx.x;
    int i0 = b * SCAN_CHUNK + t * 4;
    int s = 0;
#pragma unroll
    for (int k = 0; k < 4; k++)
        if (i0 + k < NBINS) s += bins[i0 + k];
    red[t] = s;
    __syncthreads();
    for (int off = 128; off > 0; off >>= 1) {
        if (t < off) red[t] += red[t + off];
        __syncthreads();
    }
    if (t == 0) blocksum[b] = red[0];
}

__global__ __launch_bounds__(512) void scan_pass2(const int* __restrict__ blocksum,
                                                  int* __restrict__ blockoff,
                                                  int* __restrict__ rowptr) {
    __shared__ int s[512];
    int t = threadIdx.x;
    int v = (t < NBLK) ? blocksum[t] : 0;
    s[t] = v;
    __syncthreads();
    for (int off = 1; off < 512; off <<= 1) {
        int x = (t >= off) ? s[t - off] : 0;
        __syncthreads();
        s[t] += x;
        __syncthreads();
    }
    if (t < NBLK) blockoff[t] = s[t] - v;
    if (t == 0) rowptr[NBINS] = NEDGES;
}

__global__ __launch_bounds__(256) void scan_pass3(const int* __restrict__ bins,
                                                  const int* __restrict__ blockoff,
                                                  int* __restrict__ rowptr,
                                                  int* __restrict__ cursor) {
    __shared__ int sc[256];
    int b = blockIdx.x, t = threadIdx.x;
    int i0 = b * SCAN_CHUNK + t * 4;
    int v[4], p[4];
    int s = 0;
#pragma unroll
    for (int k = 0; k < 4; k++) {
        v[k] = (i0 + k < NBINS) ? bins[i0 + k] : 0;
        p[k] = s;
        s += v[k];
    }
    sc[t] = s;
    __syncthreads();
    for (int off = 1; off < 256; off <<= 1) {
        int x = (t >= off) ? sc[t - off] : 0;
        __syncthreads();
        sc[t] += x;
        __syncthreads();
    }
    int base = blockoff[b] + (sc[t] - s);
#pragma unroll
    for (int k = 0; k < 4; k++) {
        if (i0 + k < NBINS) {
            rowptr[i0 + k] = base + p[k];
            cursor[i0 + k] = base + p[k];
        }
    }
}

__global__ void place_kernel(const int* __restrict__ dst, const int* __restrict__ src,
                             const int* __restrict__ etype,
                             int* __restrict__ cursor, int* __restrict__ bsrc) {
    int e = blockIdx.x * blockDim.x + threadIdx.x;
    if (e < NEDGES) {
        int bin = etype[e] * NNODES + dst[e];
        int pos = atomicAdd(&cursor[bin], 1);
        bsrc[pos] = src[e];
    }
}

// ---------------- converts ----------------
// Wt2[l][n][r*128+kk] = bf16(W[l][r][kk][n])   (r-major K)

__global__ __launch_bounds__(256) void convert_w(const float* __restrict__ W,
                                                 short* __restrict__ Wt2) {
    int lr = blockIdx.x;
    int l = lr / NREL, r = lr - l * NREL;
    const float* w = W + (size_t)lr * HID * HID;
    short* o = Wt2 + (size_t)l * HID * KTOT;
    int tid = threadIdx.x;
#pragma unroll 4
    for (int i = 0; i < 64; i++) {
        int elem = i * 256 + tid;
        int kk = elem >> 7, n = elem & 127;
        o[(size_t)n * KTOT + r * HID + kk] = f2bf(w[elem]);
    }
}

__global__ __launch_bounds__(256) void convert_emb(const float* __restrict__ E,
                                                   short* __restrict__ Ebf) {
    int gid = blockIdx.x * blockDim.x + threadIdx.x;
    const float* p = E + (size_t)gid * 8;
    float4 v0 = *(const float4*)p;
    float4 v1 = *(const float4*)(p + 4);
    short8 o = {f2bf(v0.x), f2bf(v0.y), f2bf(v0.z), f2bf(v0.w),
                f2bf(v1.x), f2bf(v1.y), f2bf(v1.z), f2bf(v1.w)};
    *(short8*)(Ebf + (size_t)gid * 8) = o;
}

// ---------------- fused layer: gather(bin sums) + GEMM + bias + act ----------------
// Per block: 32 dest rows, 1563 blocks (6.1/CU). Loop r=0..8:
//   prefetch B-frags (regs, global, L2-hot) -> gather H[src] sums (regs) ->
//   write bf16 A-tile into As[r&1] -> ONE barrier -> MFMA.
// Double-buffered As: write of rel r+2 separated from reads of rel r by the
// barrier at r+1 -> single barrier per relation is race-free.
// Wave shape: 32M x 32N. C mapping: row = mt*16 + lq*4 + reg, col = n0 + nt*16 + lm.

__global__ __launch_bounds__(256, 4) void fused_kernel(const short* __restrict__ Hin,
                                                       const short* __restrict__ Wt2l,
                                                       const float* __restrict__ Bias, // [9][128]
                                                       const int* __restrict__ rowptr,
                                                       const int* __restrict__ bsrc,
                                                       short* __restrict__ HoutBf,     // !last
                                                       float* __restrict__ HoutF,      // last
                                                       int last) {
    __shared__ short As[2][GM2 * FPITCH];         // 2 x 8704 B, [0] reused as Et
    __shared__ int   rp_s[NREL * (GM2 + 1)];      // 297 ints
    __shared__ float bias_s[NREL * HID];          // 4608 B

    int tid  = threadIdx.x;
    int wave = tid >> 6, lane = tid & 63;
    int lm = lane & 15, lq = lane >> 4;
    int row0 = blockIdx.x * GM2;
    int n0   = wave * 32;                 // wave's N base

    // stage rowptr spans (9 relations x 33 entries) and bias
    for (int i = tid; i < NREL * (GM2 + 1); i += 256) {
        int r = i / (GM2 + 1), o = i - r * (GM2 + 1);
        int d = row0 + o; if (d > NNODES) d = NNODES;   // clamp -> cnt 0 for pad rows
        rp_s[i] = rowptr[r * NNODES + d];
    }
    for (int i = tid; i < NREL * HID; i += 256) bias_s[i] = Bias[i];

    // gather mapping: 8 threads per dest row, 16 cols each
    int grow = tid >> 3;          // 0..31
    int gcc  = tid & 3;           // reuse below as tid&7
    gcc = tid & 7;

    f32x4 acc[2][2];
#pragma unroll
    for (int a = 0; a < 2; a++)
#pragma unroll
        for (int b = 0; b < 2; b++) acc[a][b] = (f32x4){0.f, 0.f, 0.f, 0.f};

    __syncthreads();

    const short* wb = Wt2l + (size_t)(n0 + lm) * KTOT + lq * 8;

    for (int r = 0; r < NREL; r++) {
        short* Ap = &As[r & 1][0];

        // ---- B prefetch: 8 independent 16B loads, consumed after the barrier ----
        short8 bfr[2][4];
#pragma unroll
        for (int nt = 0; nt < 2; nt++)
#pragma unroll
            for (int ks = 0; ks < 4; ks++)
                bfr[nt][ks] = *(const short8*)(wb + (size_t)nt * 16 * KTOT + r * HID + ks * 32);

        // ---- gather phase (registers only; 2-edge unrolled) ----
        int rs = rp_s[r * (GM2 + 1) + grow];
        int re = rp_s[r * (GM2 + 1) + grow + 1];
        float ga[16];
#pragma unroll
        for (int i = 0; i < 16; i++) ga[i] = 0.f;
        int j = rs;
        while (j + 1 < re) {
            int s0 = bsrc[j];
            int s1 = bsrc[j + 1];
            const short8* h0 = (const short8*)(Hin + (size_t)s0 * HID + gcc * 16);
            const short8* h1 = (const short8*)(Hin + (size_t)s1 * HID + gcc * 16);
            short8 a0 = h0[0], a1 = h0[1];
            short8 b0 = h1[0], b1 = h1[1];
#pragma unroll
            for (int i = 0; i < 8; i++) {
                ga[i]     += bf2f(a0[i]) + bf2f(b0[i]);
                ga[i + 8] += bf2f(a1[i]) + bf2f(b1[i]);
            }
            j += 2;
        }
        if (j < re) {
            int s0 = bsrc[j];
            const short8* h0 = (const short8*)(Hin + (size_t)s0 * HID + gcc * 16);
            short8 a0 = h0[0], a1 = h0[1];
#pragma unroll
            for (int i = 0; i < 8; i++) {
                ga[i]     += bf2f(a0[i]);
                ga[i + 8] += bf2f(a1[i]);
            }
        }

        // ---- convert + LDS write (own slot; no WAR hazard: see double-buffer note) ----
        {
            short8 o0, o1;
#pragma unroll
            for (int i = 0; i < 8; i++) {
                o0[i] = f2bf(ga[i]);
                o1[i] = f2bf(ga[i + 8]);
            }
            short8* ap = (short8*)&Ap[grow * FPITCH + gcc * 16];
            ap[0] = o0; ap[1] = o1;
        }
        __syncthreads();

        // ---- MFMA phase: A from LDS, B already in registers ----
#pragma unroll
        for (int ks = 0; ks < 4; ks++) {
            short8 af0 = *(const short8*)&Ap[(lm     ) * FPITCH + ks * 32 + lq * 8];
            short8 af1 = *(const short8*)&Ap[(lm + 16) * FPITCH + ks * 32 + lq * 8];
            __builtin_amdgcn_s_setprio(1);
            acc[0][0] = __builtin_amdgcn_mfma_f32_16x16x32_bf16(af0, bfr[0][ks], acc[0][0], 0, 0, 0);
            acc[1][0] = __builtin_amdgcn_mfma_f32_16x16x32_bf16(af1, bfr[0][ks], acc[1][0], 0, 0, 0);
            acc[0][1] = __builtin_amdgcn_mfma_f32_16x16x32_bf16(af0, bfr[1][ks], acc[0][1], 0, 0, 0);
            acc[1][1] = __builtin_amdgcn_mfma_f32_16x16x32_bf16(af1, bfr[1][ks], acc[1][1], 0, 0, 0);
            __builtin_amdgcn_s_setprio(0);
        }
        // no trailing barrier: next relation writes the OTHER buffer; waves that
        // finish MFMA early immediately start the next gather (imbalance smoothing)
    }

    __syncthreads();   // last MFMA read As[0] (r=8); safe to reuse as Et after this

    // ---- epilogue: counts-weighted bias, activation, store ----
    if (!last) {
        short (*Et)[FPITCH] = (short(*)[FPITCH])&As[0][0];
#pragma unroll
        for (int mt = 0; mt < 2; mt++) {
#pragma unroll
            for (int reg = 0; reg < 4; reg++) {
                int rl = mt * 16 + lq * 4 + reg;
                float cr[NREL];
#pragma unroll
                for (int rr = 0; rr < NREL; rr++)
                    cr[rr] = (float)(rp_s[rr * (GM2 + 1) + rl + 1] - rp_s[rr * (GM2 + 1) + rl]);
#pragma unroll
                for (int nt = 0; nt < 2; nt++) {
                    int n = n0 + nt * 16 + lm;
                    float b = 0.f;
#pragma unroll
                    for (int rr = 0; rr < NREL; rr++) b += cr[rr] * bias_s[rr * HID + n];
                    float o = fmaxf(acc[mt][nt][reg] + b, 0.f);
                    Et[rl][n] = f2bf(o);
                }
            }
        }
        __syncthreads();
#pragma unroll
        for (int i = 0; i < 2; i++) {
            int p = i * 256 + tid;
            int row = p >> 4, cc = p & 15;
            int d = row0 + row;
            if (d < NNODES)
                *(short8*)(HoutBf + (size_t)d * HID + cc * 8) = *(const short8*)&Et[row][cc * 8];
        }
    } else {
#pragma unroll
        for (int mt = 0; mt < 2; mt++) {
#pragma unroll
            for (int reg = 0; reg < 4; reg++) {
                int rl = mt * 16 + lq * 4 + reg;
                int d  = row0 + rl;
                if (d >= NNODES) continue;
                float cr[NREL];
#pragma unroll
                for (int rr = 0; rr < NREL; rr++)
                    cr[rr] = (float)(rp_s[rr * (GM2 + 1) + rl + 1] - rp_s[rr * (GM2 + 1) + rl]);
#pragma unroll
                for (int nt = 0; nt < 2; nt++) {
                    int n = n0 + nt * 16 + lm;
                    float b = 0.f;
#pragma unroll
                    for (int rr = 0; rr < NREL; rr++) b += cr[rr] * bias_s[rr * HID + n];
                    HoutF[(size_t)d * HID + n] = acc[mt][nt][reg] + b;
                }
            }
        }
    }
}

// ---------------- driver ----------------

extern "C" void kernel_launch(void* const* d_in, const int* in_sizes, int n_in,
                              void* d_out, int out_size, void* d_ws, size_t ws_size,
                              hipStream_t stream) {
    const int*   edge_index = (const int*)d_in[0];   // [2, NEDGES]: row0=dest, row1=src
    const int*   etype      = (const int*)d_in[1];
    const float* emb        = (const float*)d_in[2];
    const float* W          = (const float*)d_in[3]; // [3,9,128,128]
    const float* Bias       = (const float*)d_in[4]; // [3,9,128]
    float*       out        = (float*)d_out;

    const int* dst  = edge_index;
    const int* srcA = edge_index + NEDGES;

    // ws layout (H double-buffered across layers)
    short* Ebf  = (short*)d_ws;                             // 50000*128 bf16
    short* HbfA = Ebf  + (size_t)NNODES * HID;              // 50000*128 bf16
    short* HbfB = HbfA + (size_t)NNODES * HID;              // 50000*128 bf16
    short* Wt2  = HbfB + (size_t)NNODES * HID;              // 3*128*1152 bf16
    int*   bsrc     = (int*)(Wt2 + (size_t)NLAYERS * HID * KTOT);
    int*   bins     = bsrc + NEDGES;
    int*   cursor   = bins + NBINS;
    int*   rowptr   = cursor + NBINS;                       // NBINS+1
    int*   blocksum = rowptr + NBINS + 1;
    int*   blockoff = blocksum + NBLK;

    hipMemsetAsync(bins, 0, NBINS * sizeof(int), stream);
    hist2_kernel<<<(NEDGES + 255) / 256, 256, 0, stream>>>(dst, etype, bins);
    scan_pass1<<<NBLK, 256, 0, stream>>>(bins, blocksum);
    scan_pass2<<<1, 512, 0, stream>>>(blocksum, blockoff, rowptr);
    scan_pass3<<<NBLK, 256, 0, stream>>>(bins, blockoff, rowptr, cursor);
    place_kernel<<<(NEDGES + 255) / 256, 256, 0, stream>>>(dst, srcA, etype, cursor, bsrc);
    convert_w<<<NLAYERS * NREL, 256, 0, stream>>>(W, Wt2);
    convert_emb<<<(NNODES * HID / 8) / 256, 256, 0, stream>>>(emb, Ebf);

    const int nblocks = (NNODES + GM2 - 1) / GM2;   // 1563
    const short* Hin = Ebf;
    for (int l = 0; l < NLAYERS; l++) {
        int last = (l + 1 == NLAYERS);
        short* Hout = (l == 0) ? HbfA : HbfB;       // alternate; never in-place
        if (l == 2) Hout = HbfA;                    // unused on last layer
        const short* Wtl = Wt2 + (size_t)l * HID * KTOT;
        const float* Bl  = Bias + (size_t)l * NREL * HID;
        fused_kernel<<<nblocks, 256, 0, stream>>>(
            Hin, Wtl, Bl, rowptr, bsrc, Hout, out, last);
        Hin = Hout;
    }
}